// Round 8
// baseline (602.530 us; speedup 1.0000x reference)
//
#include <hip/hip_runtime.h>
#include <hip/hip_bf16.h>
#include <math.h>

// Problem constants
constexpr int NN  = 16000;          // nodes
constexpr int NE  = 256000;         // edges (original)
constexpr int NET = NE + NN;        // edges incl. self loops
constexpr int NK  = 4000;           // top-k
constexpr int NH  = 4;              // heads
constexpr int ND  = 128;            // dim
constexpr int NCL = 16;             // clusters

// acc buffer sub-offsets (floats)
constexpr int A_ADJ    = 0;     // 256  raw s^T adj s
constexpr int A_SS     = 256;   // 256  s^T s
constexpr int A_CSUM   = 512;   // 16   sum_n s[n,c]
constexpr int A_V      = 528;   // 16   sum_n s[n,c]*deg[n]
constexpr int A_DEGSUM = 544;   // 1
constexpr int A_OUTX   = 560;   // 2048 s^T xp (selu'd in k_finloss)
constexpr int A_ADJN   = 2608;  // 256  normalized adjacency
constexpr int ACC_FLOATS = 3072;

typedef short sh8 __attribute__((ext_vector_type(8)));
typedef float f32x4 __attribute__((ext_vector_type(4)));

__device__ inline unsigned fkey(float f){
  unsigned u = __float_as_uint(f);
  return (u & 0x80000000u) ? ~u : (u | 0x80000000u);
}

__device__ inline unsigned short f2bf(float f){
  unsigned u = __float_as_uint(f);
  unsigned r = u + 0x7FFFu + ((u>>16)&1u);   // round-to-nearest-even
  return (unsigned short)(r>>16);
}

__device__ inline float bf2f(unsigned short v){
  return __uint_as_float(((unsigned)v)<<16);
}

// ---------------- init ----------------
__global__ void k_init(int* cnt, int* node2k, float* tbuf, float* deg, float* acc){
  int i = blockIdx.x*blockDim.x + threadIdx.x;
  int stride = gridDim.x*blockDim.x;
  for (int j=i; j<NN; j+=stride){ cnt[j]=0; node2k[j]=-1; }
  for (int j=i; j<NK*NCL; j+=stride) tbuf[j]=0.f;
  for (int j=i; j<NK; j+=stride) deg[j]=0.f;
  for (int j=i; j<ACC_FLOATS; j+=stride) acc[j]=0.f;
}

// ---------------- CSR build ----------------
__global__ void k_count(const int* __restrict__ ei, int* __restrict__ cnt){
  int e = blockIdx.x*blockDim.x + threadIdx.x;
  if (e >= NET) return;
  int d = (e < NE) ? ei[NE+e] : (e-NE);
  atomicAdd(&cnt[d], 1);
}

__global__ __launch_bounds__(1024) void k_scan(int* cnt, int* ptr, int* fill){
  __shared__ int sums[1024];
  int t = threadIdx.x;
  constexpr int PER = 16;            // 1024*16 = 16384 >= NN
  int base = t*PER;
  int v[PER];
  int run = 0;
  #pragma unroll
  for (int i=0;i<PER;i++){
    int idx = base+i;
    int c = (idx<NN)? cnt[idx] : 0;
    v[i] = run; run += c;
  }
  sums[t] = run;
  __syncthreads();
  for (int o=1;o<1024;o<<=1){
    int add = (t>=o)? sums[t-o] : 0;
    __syncthreads();
    sums[t] += add;
    __syncthreads();
  }
  int ex = sums[t] - run;
  #pragma unroll
  for (int i=0;i<PER;i++){
    int idx = base+i;
    if (idx<NN){ int p = ex+v[i]; ptr[idx]=p; fill[idx]=p; }
  }
  if (t==1023) ptr[NN]=sums[1023];
}

__global__ void k_fill(const int* __restrict__ ei, int* cur, int* csrc){
  int e = blockIdx.x*blockDim.x + threadIdx.x;
  if (e >= NET) return;
  int s, d;
  if (e < NE){ s = ei[e]; d = ei[NE+e]; } else { s = e-NE; d = e-NE; }
  int pos = atomicAdd(&cur[d], 1);
  csrc[pos] = s;
}

// ---------------- embedding (fp32 + bf16 copies) ----------------
__global__ void k_embed(const int* __restrict__ x, const float* __restrict__ emb,
                        float4* __restrict__ h, unsigned short* __restrict__ hbf){
  int i = blockIdx.x*blockDim.x + threadIdx.x;
  if (i >= NN*32) return;
  int n = i >> 5, q = i & 31;
  float4 v = ((const float4*)emb)[(size_t)x[n]*32 + q];
  h[i] = v;
  ushort4 b;
  b.x = f2bf(v.x); b.y = f2bf(v.y); b.z = f2bf(v.z); b.w = f2bf(v.w);
  ((ushort4*)hbf)[i] = b;
}

// ---------------- combined per-layer prep: usd vectors + W pack ----------------
// blocks 0..31: Blay[((c*16+kc)*64 + lane)*8 + j] = B2[d][kk] (bf16 MFMA-B layout)
// block 32:     usd (u_s, u_d attention vectors)
__global__ __launch_bounds__(256) void k_prepc(const float* __restrict__ W,
                                               const float* __restrict__ as_,
                                               const float* __restrict__ ad_,
                                               float* __restrict__ usd,
                                               unsigned short* __restrict__ Blay){
  int b = blockIdx.x;
  if (b < 32){
    int idx = b*256 + threadIdx.x;  // 0..8191
    int lane = idx&63, kc = (idx>>6)&15, c = idx>>10;
    int d = c*16 + (lane&15), q = lane>>4;
    sh8 v;
    #pragma unroll
    for (int j=0;j<8;j++){
      int kkg = kc*32 + q*8 + j;
      int h = kkg>>7, k = kkg&127;
      v[j] = (short)f2bf(W[(size_t)(h*128+d)*128 + k]);
    }
    *((sh8*)(Blay + (size_t)idx*8)) = v;
  } else {
    for (int t = threadIdx.x; t < 512; t += 256){
      int h = t>>7, k = t&127;
      float ss=0.f, sd=0.f;
      for (int d=0; d<128; d++){
        float w = W[(size_t)(h*128+d)*128 + k];
        ss += as_[h*128+d]*w;
        sd += ad_[h*128+d]*w;
      }
      usd[t] = ss;
      usd[512+t] = sd;
    }
  }
}

// ---------------- pack dmon_w into MFMA-B layout (one-time) ----------------
__global__ void k_prepdw(const float* __restrict__ dw, unsigned short* __restrict__ dwb){
  int idx = threadIdx.x;            // 256 = 4 kc * 64 lanes
  int kc = idx>>6, lane = idx&63;
  int c = lane&15, q = lane>>4;
  sh8 v;
  #pragma unroll
  for (int j=0;j<8;j++) v[j] = (short)f2bf(dw[(size_t)c*128 + kc*32 + q*8 + j]);
  ((sh8*)dwb)[idx] = v;
}

// ---------------- attention logit sums (bf16 features) ----------------
__global__ void k_attnsum(const unsigned short* __restrict__ hbf, const float* __restrict__ usd,
                          float* __restrict__ sum_s, float* __restrict__ sum_d){
  int n = blockIdx.x, lane = threadIdx.x;   // 64 threads
  const unsigned short* row = hbf + (size_t)n*128;
  float x0 = bf2f(row[lane]), x1 = bf2f(row[64+lane]);
  for (int h=0;h<4;h++){
    float ps = x0*usd[h*128+lane]     + x1*usd[h*128+64+lane];
    float pd = x0*usd[512+h*128+lane] + x1*usd[512+h*128+64+lane];
    #pragma unroll
    for (int off=32; off>0; off>>=1){ ps += __shfl_down(ps,off); pd += __shfl_down(pd,off); }
    if (lane==0){ sum_s[n*4+h]=ps; sum_d[n*4+h]=pd; }
  }
}

// ---------------- edge softmax (per dst,head), writes pre-scaled packed bf16 alpha ----
__global__ void k_edges(const int* __restrict__ ptr, const int* __restrict__ csrc,
                        const float* __restrict__ sum_s, const float* __restrict__ sum_d,
                        float* __restrict__ logits, unsigned short* __restrict__ alphab){
  int idx = blockIdx.x*blockDim.x + threadIdx.x;
  if (idx >= NN*NH) return;
  int n = idx >> 2, h = idx & 3;
  int b0 = ptr[n], b1 = ptr[n+1];
  float sd = sum_d[n*4+h];
  float mx = -1e30f;
  for (int j=b0;j<b1;j++){
    float v = sum_s[csrc[j]*4+h] + sd;
    v = v > 0.f ? v : 0.2f*v;
    logits[(size_t)j*4+h] = v;
    mx = fmaxf(mx, v);
  }
  float den = 0.f;
  for (int j=b0;j<b1;j++) den += __expf(logits[(size_t)j*4+h] - mx);
  float scale = 0.25f/(den + 1e-16f);
  for (int j=b0;j<b1;j++)
    alphab[(size_t)j*4+h] = f2bf(__expf(logits[(size_t)j*4+h] - mx)*scale);
}

// ---------------- input-space aggregation (bf16 gather, bf16 out) ----------------
__global__ void k_agg(const int* __restrict__ ptr, const int* __restrict__ csrc,
                      const unsigned short* __restrict__ alphab,
                      const unsigned short* __restrict__ hbf,
                      unsigned short* __restrict__ agg){
  int n = blockIdx.x; int t = threadIdx.x;  // 128 threads
  int b0 = ptr[n], b1 = ptr[n+1];
  float a0=0.f, a1=0.f, a2=0.f, a3=0.f;
  for (int j=b0;j<b1;j++){
    int s = csrc[j];
    ushort4 al = *(const ushort4*)&alphab[(size_t)j*4];
    float v = bf2f(hbf[(size_t)s*128 + t]);
    a0 += bf2f(al.x)*v; a1 += bf2f(al.y)*v;
    a2 += bf2f(al.z)*v; a3 += bf2f(al.w)*v;
  }
  unsigned short* o = agg + (size_t)n*512;
  o[t]     = f2bf(a0);
  o[128+t] = f2bf(a1);
  o[256+t] = f2bf(a2);
  o[384+t] = f2bf(a3);
}

// ---------------- MFMA head-transform GEMM (writes fp32 h + bf16 copy) ----------
__global__ __launch_bounds__(256) void k_gemmb(const unsigned short* __restrict__ A,
                                               const unsigned short* __restrict__ B,
                                               const float* __restrict__ bias,
                                               float* __restrict__ C,
                                               unsigned short* __restrict__ Cb){
  int tid = threadIdx.x;
  int w = tid>>6, lane = tid&63;
  int m0 = blockIdx.x*64 + w*16;
  int quad = lane>>4;
  int mrow = m0 + (lane&15);
  const sh8* arow = (const sh8*)(A + (size_t)mrow*512 + quad*8);
  sh8 af[16];
  #pragma unroll
  for (int kc=0;kc<16;kc++) af[kc] = arow[kc*4];
  f32x4 acc[8];
  #pragma unroll
  for (int c=0;c<8;c++) acc[c] = (f32x4){0.f,0.f,0.f,0.f};
  const sh8* bp = (const sh8*)B;
  #pragma unroll
  for (int kc=0;kc<16;kc++){
    #pragma unroll
    for (int c=0;c<8;c++){
      sh8 bf = bp[(c*16+kc)*64 + lane];
      acc[c] = __builtin_amdgcn_mfma_f32_16x16x32_bf16(af[kc], bf, acc[c], 0, 0, 0);
    }
  }
  #pragma unroll
  for (int c=0;c<8;c++){
    int d = c*16 + (lane&15);
    float bi = bias[d];
    #pragma unroll
    for (int r=0;r<4;r++){
      int m = m0 + quad*4 + r;
      float v = fmaxf(acc[c][r] + bi, 0.f);
      C[(size_t)m*128 + d] = v;
      Cb[(size_t)m*128 + d] = f2bf(v);
    }
  }
}

// ---------------- SAG score (algebraic: scalar per node) ----------------
__global__ void k_pq(const float* __restrict__ h, const float* __restrict__ wrel,
                     const float* __restrict__ wroot, float* __restrict__ p,
                     float* __restrict__ q){
  int n = blockIdx.x; int lane = threadIdx.x; // 64
  const float* row = h+(size_t)n*128;
  float a = row[lane]*wrel[lane] + row[64+lane]*wrel[64+lane];
  float b = row[lane]*wroot[lane] + row[64+lane]*wroot[64+lane];
  #pragma unroll
  for (int o=32;o>0;o>>=1){ a += __shfl_down(a,o); b += __shfl_down(b,o); }
  if (lane==0){ p[n]=a; q[n]=b; }
}

__global__ void k_sagscore(const int* __restrict__ ptr, const int* __restrict__ csrc,
                           const float* __restrict__ p, const float* __restrict__ q,
                           const float* __restrict__ brel, float* __restrict__ score){
  int n = blockIdx.x*blockDim.x + threadIdx.x;
  if (n >= NN) return;
  int b0=ptr[n], b1=ptr[n+1];
  float s=0.f;
  for (int j=b0;j<b1;j++){ int sj=csrc[j]; if (sj!=n) s+=p[sj]; }
  score[n] = s + q[n] + brel[0];
}

// ---------------- fused single-block radix top-k (register-resident keys) ----------------
__global__ __launch_bounds__(1024) void k_topk(const float* __restrict__ score,
                                               int* __restrict__ sel){
  __shared__ int hist[8*257];
  __shared__ int hmerge[256];
  __shared__ unsigned sh_prefix;
  __shared__ int sh_rem;
  __shared__ int cntGT, cntEQ;
  __shared__ int ties[256];
  int t = threadIdx.x;
  int lane = t & 63;
  int rep = t >> 7;
  unsigned keys[16];
  #pragma unroll
  for (int j=0;j<16;j++){
    int i = t + j*1024;
    keys[j] = (i<NN) ? fkey(score[i]) : 0u;
  }
  if (t==0){ sh_prefix=0u; sh_rem=NK; cntGT=0; cntEQ=0; }
  __syncthreads();
  for (int p=0;p<4;p++){
    int shift = 24-8*p;
    for (int i=t;i<8*257;i+=1024) hist[i]=0;
    __syncthreads();
    unsigned prefix = sh_prefix;
    #pragma unroll
    for (int j=0;j<16;j++){
      bool val = (j<15) || (t < (NN - 15*1024));
      unsigned u = keys[j];
      bool ok = val && ((p==0) || ((u>>(shift+8)) == (prefix>>(shift+8))));
      int b = (int)((u>>shift)&255u);
      unsigned long long act = __ballot(ok);
      if (act){
        int leader = (int)(__ffsll((long long)act)-1);
        int bl = __shfl(b, leader);
        unsigned long long same = __ballot(ok && b==bl);
        if (same==act){
          if (lane==leader) atomicAdd(&hist[rep*257+bl], (int)__popcll(act));
        } else if (ok){
          atomicAdd(&hist[rep*257+b], 1);
        }
      }
    }
    __syncthreads();
    if (t<256){
      int v=0;
      #pragma unroll
      for (int r=0;r<8;r++) v += hist[r*257+t];
      hmerge[t]=v;
    }
    __syncthreads();
    if (t<64){
      int l = t;
      int b0 = 4*(63-l);
      int c3 = hmerge[b0+3], c2 = hmerge[b0+2], c1 = hmerge[b0+1], c0 = hmerge[b0];
      int gs = c0+c1+c2+c3;
      int incl = gs;
      #pragma unroll
      for (int o=1;o<64;o<<=1){
        int v = __shfl_up(incl, o);
        if (l>=o) incl += v;
      }
      int excl = incl - gs;
      int rem = sh_rem;
      int rl = rem - excl;
      if (rl > 0 && rl <= gs){
        unsigned pre = sh_prefix;
        if (rl > c3){ rl -= c3;
          if (rl > c2){ rl -= c2;
            if (rl > c1){ rl -= c1;
              sh_prefix = pre | ((unsigned)b0<<shift);     sh_rem = rl;
            } else { sh_prefix = pre | ((unsigned)(b0+1)<<shift); sh_rem = rl; }
          } else { sh_prefix = pre | ((unsigned)(b0+2)<<shift);   sh_rem = rl; }
        } else { sh_prefix = pre | ((unsigned)(b0+3)<<shift);     sh_rem = rl; }
      }
    }
    __syncthreads();
  }
  unsigned Tu = sh_prefix;
  #pragma unroll
  for (int j=0;j<16;j++){
    int i = t + j*1024;
    bool val = (i<NN);
    unsigned u = keys[j];
    bool g = val && (u>Tu), e = val && (u==Tu);
    unsigned long long mg = __ballot(g);
    if (mg){
      int leader = (int)(__ffsll((long long)mg)-1);
      int base = 0;
      if (lane==leader) base = atomicAdd(&cntGT, (int)__popcll(mg));
      base = __shfl(base, leader);
      if (g){
        int pos = base + (int)__popcll(mg & ((1ull<<lane)-1ull));
        sel[pos] = i;
      }
    }
    unsigned long long me = __ballot(e);
    if (me){
      int leader = (int)(__ffsll((long long)me)-1);
      int base = 0;
      if (lane==leader) base = atomicAdd(&cntEQ, (int)__popcll(me));
      base = __shfl(base, leader);
      if (e){
        int pos = base + (int)__popcll(me & ((1ull<<lane)-1ull));
        if (pos<256) ties[pos] = i;
      }
    }
  }
  __syncthreads();
  if (t==0){
    int base=cntGT, rem=sh_rem, nt=min(cntEQ,256);
    for (int r=0;r<rem;r++){
      int best=0x7fffffff, bi=-1;
      for (int q2=0;q2<nt;q2++){ int v=ties[q2]; if (v>=0 && v<best){best=v;bi=q2;} }
      sel[base+r] = (bi>=0)? best : 0;
      if (bi>=0) ties[bi]=-1;
    }
  }
}

// ---------------- xp gather + node2k (fp32 + bf16) ----------------
__global__ void k_gatherx(const int* __restrict__ sel, const float* __restrict__ score,
                          const float* __restrict__ h, float* __restrict__ xp,
                          unsigned short* __restrict__ xpb, int* __restrict__ node2k){
  int k = blockIdx.x; int t = threadIdx.x; // 128
  int n = sel[k];
  if (t==0) node2k[n] = k;
  float g = tanhf(score[n]);
  float v = h[(size_t)n*128+t]*g;
  xp[(size_t)k*128+t] = v;
  xpb[(size_t)k*128+t] = f2bf(v);
}

// ---------------- DMoN assignment softmax (MFMA) ----------------
__global__ __launch_bounds__(64) void k_assignm(const unsigned short* __restrict__ xpb,
                                                const unsigned short* __restrict__ dwb,
                                                const float* __restrict__ db,
                                                float* __restrict__ sA){
  int k0 = blockIdx.x*16;
  int lane = threadIdx.x;
  int quad = lane>>4, col = lane&15;
  const sh8* ar = (const sh8*)(xpb + (size_t)(k0+col)*128 + quad*8);
  const sh8* br = (const sh8*)dwb;
  f32x4 acc = (f32x4){0.f,0.f,0.f,0.f};
  #pragma unroll
  for (int kc=0;kc<4;kc++){
    sh8 af = ar[kc*4];
    sh8 bf = br[kc*64 + lane];
    acc = __builtin_amdgcn_mfma_f32_16x16x32_bf16(af, bf, acc, 0, 0, 0);
  }
  float bias = db[col];
  #pragma unroll
  for (int r=0;r<4;r++){
    float lg = acc[r] + bias;
    float mx = lg;
    #pragma unroll
    for (int o=1;o<16;o<<=1) mx = fmaxf(mx, __shfl_xor(mx, o));
    float e = __expf(lg - mx);
    float sm = e;
    #pragma unroll
    for (int o=1;o<16;o<<=1) sm += __shfl_xor(sm, o);
    sA[(size_t)(k0+quad*4+r)*16 + col] = e/sm;
  }
}

// ---------------- pooled adjacency ----------------
__global__ void k_edgepool(const int* __restrict__ ei, const int* __restrict__ node2k,
                           const float* __restrict__ sA, float* __restrict__ tbuf,
                           float* __restrict__ deg){
  int e = blockIdx.x*blockDim.x + threadIdx.x;
  if (e >= NE) return;
  int ni = node2k[ei[e]];
  int nj = node2k[ei[NE+e]];
  if (ni >= 0 && nj >= 0){
    atomicAdd(&deg[nj], 1.f);
    const float* sr = &sA[(size_t)nj*16];
    float* tr = &tbuf[(size_t)ni*16];
    #pragma unroll
    for (int c=0;c<16;c++) atomicAdd(&tr[c], sr[c]);
  }
}

// ---------------- fused pooled reductions ----------------
constexpr int P_BLOCKS = 32;
constexpr int P_ROWS   = NK / P_BLOCKS;   // 125
constexpr int P_CHUNK  = 25;

__global__ __launch_bounds__(256) void k_pool(const float* __restrict__ sA,
                                              const float* __restrict__ xp,
                                              const float* __restrict__ tb,
                                              const float* __restrict__ deg,
                                              float* __restrict__ acc){
  __shared__ float sv[P_CHUNK*16];
  __shared__ float tv[P_CHUNK*16];
  __shared__ float dv[P_CHUNK];
  __shared__ float xv[P_CHUNK*128];
  int t = threadIdx.x;
  int c = t>>4, d = t&15;
  float loc[8] = {0,0,0,0,0,0,0,0};
  float a_adj=0.f, a_ss=0.f, a_cs=0.f, a_v=0.f, a_dg=0.f;
  int r0 = blockIdx.x*P_ROWS;
  for (int ch=0; ch<P_ROWS; ch+=P_CHUNK){
    int base = r0+ch;
    for (int i=t;i<P_CHUNK*16;i+=256){
      sv[i] = sA[(size_t)(base+(i>>4))*16 + (i&15)];
      tv[i] = tb[(size_t)(base+(i>>4))*16 + (i&15)];
    }
    for (int i=t;i<P_CHUNK*128;i+=256)
      xv[i] = xp[(size_t)(base+(i>>7))*128 + (i&127)];
    if (t<P_CHUNK) dv[t]=deg[base+t];
    __syncthreads();
    for (int r=0;r<P_CHUNK;r++){
      float sc = sv[r*16+c];
      a_adj += sc*tv[r*16+d];
      a_ss  += sc*sv[r*16+d];
      if (d==0){ a_cs += sc; a_v += sc*dv[r]; }
      if (t==0) a_dg += dv[r];
      #pragma unroll
      for (int j=0;j<8;j++){
        int o=t+j*256;
        loc[j] += sv[r*16+(o>>7)]*xv[r*128+(o&127)];
      }
    }
    __syncthreads();
  }
  atomicAdd(&acc[A_ADJ + t], a_adj);
  atomicAdd(&acc[A_SS + t], a_ss);
  if (d==0){ atomicAdd(&acc[A_CSUM+c], a_cs); atomicAdd(&acc[A_V+c], a_v); }
  if (t==0) atomicAdd(&acc[A_DEGSUM], a_dg);
  #pragma unroll
  for (int j=0;j<8;j++) atomicAdd(&acc[A_OUTX + t + j*256], loc[j]);
}

__device__ float block_sum_256(float v, float* red){
  int t = threadIdx.x;
  red[t]=v; __syncthreads();
  #pragma unroll
  for (int o=128;o>0;o>>=1){ if (t<o) red[t]+=red[t+o]; __syncthreads(); }
  float r = red[0]; __syncthreads();
  return r;
}

// ---------------- losses + normalized adjacency + selu(out_x) ----------------
__global__ __launch_bounds__(256) void k_finloss(float* __restrict__ acc, float* __restrict__ dout){
  __shared__ float red[256];
  __shared__ float dsv[16];
  int t = threadIdx.x;
  int c = t>>4, dcol = t&15;
  float m = 0.5f*acc[A_DEGSUM];
  float ssv = acc[A_SS+t];
  float tr    = block_sum_256((t<16)? acc[A_ADJ + t*16 + t] : 0.f, red);
  float sumv2 = block_sum_256((t<16)? acc[A_V+t]*acc[A_V+t] : 0.f, red);
  float ss2   = block_sum_256(ssv*ssv, red);
  float cs2   = block_sum_256((t<16)? acc[A_CSUM+t]*acc[A_CSUM+t] : 0.f, red);
  float ssn = sqrtf(ss2);
  float term = ssv/ssn - ((c==dcol)? 0.25f : 0.f);
  float ortho2 = block_sum_256(term*term, red);
  if (t==0){
    float spectral = -(tr - sumv2/(2.f*m))/(2.f*m);
    float ortho = sqrtf(ortho2);
    float cluster = sqrtf(cs2)/(float)NK*4.f - 1.f;
    dout[1] = spectral + ortho + cluster;
  }
  float z = (c==dcol)? 0.f : acc[A_ADJ+t];
  red[t]=z; __syncthreads();
  for (int o=8;o>0;o>>=1){ if (dcol<o) red[t]+=red[t+o]; __syncthreads(); }
  if (dcol==0) dsv[c]=sqrtf(red[c*16])+1e-15f;
  __syncthreads();
  acc[A_ADJN+t] = z/(dsv[c]*dsv[dcol]);
  #pragma unroll
  for (int j=0;j<8;j++){
    int idx = t + j*256;
    float xv = acc[A_OUTX+idx];
    float s2 = (xv > 0.f)? xv : 1.6732632423543772f*expm1f(xv);
    acc[A_OUTX+idx] = 1.0507009873554805f*s2;
  }
}

// ---------------- hh = selu(out_x) @ Wt^T ----------------
__global__ void k_hh(const float* __restrict__ acc, const float* __restrict__ Wt,
                     float* __restrict__ hh){
  int of = blockIdx.x*256 + threadIdx.x; // 0..8191
  int c = of >> 9, o = of & 511;
  const float* sx = acc + A_OUTX + c*128;
  const float* w = Wt + (size_t)o*128;
  float s=0.f;
  for (int k=0;k<128;k++) s += sx[k]*w[k];
  hh[of] = s;
}

// ---------------- dense GAT head + readout ----------------
__global__ __launch_bounds__(256) void k_head(
    const float* __restrict__ hh_g, const float* __restrict__ acc,
    const float* __restrict__ att_s, const float* __restrict__ att_d,
    const float* __restrict__ bt, const float* __restrict__ gate_w,
    const float* __restrict__ gate_b, const float* __restrict__ trans_w,
    const float* __restrict__ trans_b, const int* __restrict__ task,
    const float* __restrict__ task_emb, const float* __restrict__ task_w,
    const float* __restrict__ task_b, const float* __restrict__ fuse_w,
    const float* __restrict__ fuse_b, const float* __restrict__ out_w,
    const float* __restrict__ out_b, float* __restrict__ dout){
  __shared__ float hh[8192];
  __shared__ float al[1024];
  __shared__ float asrc[64], adst[64];
  __shared__ float dg[2048];
  __shared__ float gate[16];
  __shared__ float gvec[128];
  __shared__ float ro[128], te[128], fu[128];
  __shared__ float red[256];
  int t = threadIdx.x;
  for (int i=t;i<8192;i+=256) hh[i]=hh_g[i];
  __syncthreads();
  if (t<128){
    int j = t>>3; int h = (t>>1)&3; int w = t&1;
    const float* hr = &hh[j*512 + h*128];
    const float* a = (w? att_d : att_s) + h*128;
    float s=0.f;
    for (int k2=0;k2<128;k2++) s += hr[k2]*a[k2];
    if (w) adst[j*4+h]=s; else asrc[j*4+h]=s;
  }
  __syncthreads();
  for (int idx=t; idx<1024; idx+=256){
    int h = idx&3, j=(idx>>2)&15, i=idx>>6;
    float v = asrc[j*4+h] + adst[i*4+h];
    v = v>0.f? v : 0.2f*v;
    float adjl = (i==j)? 1.f : acc[A_ADJN + i*16+j];
    al[idx] = (adjl==0.f)? -1e30f : v;
  }
  __syncthreads();
  if (t<64){
    int i=t>>2, h=t&3;
    float mx=-1e30f;
    for (int j=0;j<16;j++) mx = fmaxf(mx, al[(i*16+j)*4+h]);
    float sum=0.f;
    for (int j=0;j<16;j++){ float e=__expf(al[(i*16+j)*4+h]-mx); al[(i*16+j)*4+h]=e; sum+=e; }
    float inv = 1.f/sum;
    for (int j=0;j<16;j++) al[(i*16+j)*4+h]*=inv;
  }
  __syncthreads();
  for (int idx=t; idx<2048; idx+=256){
    int i=idx>>7, d=idx&127;
    float s=0.f;
    for (int h=0;h<4;h++)
      for (int j=0;j<16;j++)
        s += al[(i*16+j)*4+h]*hh[j*512+h*128+d];
    dg[idx] = fmaxf(0.25f*s + bt[d], 0.f);
  }
  __syncthreads();
  if (t<16){
    float s=0.f;
    for (int d2=0;d2<128;d2++) s += dg[t*128+d2]*gate_w[d2];
    red[t] = s + gate_b[0];
  }
  __syncthreads();
  if (t<16){
    float mx=-1e30f; for (int i=0;i<16;i++) mx=fmaxf(mx,red[i]);
    float s=0.f; for (int i=0;i<16;i++) s+=__expf(red[i]-mx);
    gate[t]=__expf(red[t]-mx)/s;
  }
  __syncthreads();
  if (t<128){
    float s=0.f;
    for (int i=0;i<16;i++) s += gate[i]*dg[i*128+t];
    gvec[t]=s;
  }
  __syncthreads();
  if (t<128){
    float s=0.f;
    for (int k2=0;k2<128;k2++) s += gvec[k2]*trans_w[t*128+k2];
    ro[t]=s+trans_b[t];
    int tk = task[0];
    float s2=0.f;
    for (int k2=0;k2<128;k2++) s2 += task_emb[(size_t)tk*128+k2]*task_w[t*128+k2];
    te[t]=fmaxf(s2+task_b[t],0.f);
  }
  __syncthreads();
  if (t<128){
    float s=0.f;
    for (int k2=0;k2<128;k2++) s += ro[k2]*fuse_w[t*256+k2] + te[k2]*fuse_w[t*256+128+k2];
    fu[t]=fmaxf(s+fuse_b[t],0.f);
  }
  __syncthreads();
  float v = (t<128)? fu[t]*out_w[t] : 0.f;
  red[t]=v; __syncthreads();
  for (int o=128;o>0;o>>=1){ if (t<o) red[t]+=red[t+o]; __syncthreads(); }
  if (t==0) dout[0]=red[0]+out_b[0];
}

// ================= launcher =================
extern "C" void kernel_launch(void* const* d_in, const int* in_sizes, int n_in,
                              void* d_out, int out_size, void* d_ws, size_t ws_size,
                              hipStream_t stream){
  const int* x        = (const int*)d_in[0];
  const int* ei       = (const int*)d_in[1];
  const int* task     = (const int*)d_in[3];
  const float* node_emb = (const float*)d_in[4];
  const float* task_emb = (const float*)d_in[5];
  const float* W[3]  = {(const float*)d_in[6],  (const float*)d_in[10], (const float*)d_in[14]};
  const float* As_[3]= {(const float*)d_in[7],  (const float*)d_in[11], (const float*)d_in[15]};
  const float* Ad_[3]= {(const float*)d_in[8],  (const float*)d_in[12], (const float*)d_in[16]};
  const float* Bb[3] = {(const float*)d_in[9],  (const float*)d_in[13], (const float*)d_in[17]};
  const float* wrel  = (const float*)d_in[18];
  const float* brel  = (const float*)d_in[19];
  const float* wroot = (const float*)d_in[20];
  const float* dmon_w= (const float*)d_in[21];
  const float* dmon_b= (const float*)d_in[22];
  const float* Wt    = (const float*)d_in[23];
  const float* att_s = (const float*)d_in[24];
  const float* att_d = (const float*)d_in[25];
  const float* btb   = (const float*)d_in[26];
  const float* gate_w= (const float*)d_in[27];
  const float* gate_b= (const float*)d_in[28];
  const float* trans_w=(const float*)d_in[29];
  const float* trans_b=(const float*)d_in[30];
  const float* task_w= (const float*)d_in[31];
  const float* task_b= (const float*)d_in[32];
  const float* fuse_w= (const float*)d_in[33];
  const float* fuse_b= (const float*)d_in[34];
  const float* out_w = (const float*)d_in[35];
  const float* out_b = (const float*)d_in[36];
  float* dout = (float*)d_out;
  (void)in_sizes; (void)n_in; (void)out_size; (void)ws_size;

  char* base = (char*)d_ws;
  size_t off = 0;
  auto alloc = [&](size_t bytes)->char*{
    off = (off + 255) & ~(size_t)255;
    char* r = base + off; off += bytes; return r;
  };
  int* csr_ptr  = (int*)alloc((size_t)(NN+1)*4);
  int* csr_fill = (int*)alloc((size_t)NN*4);
  int* csr_src  = (int*)alloc((size_t)NET*4);
  int* sel      = (int*)alloc((size_t)NK*4);
  int* node2k   = (int*)alloc((size_t)NN*4);
  float* score  = (float*)alloc((size_t)NN*4);
  float* pbuf   = (float*)alloc((size_t)NN*4);
  float* qbuf   = (float*)alloc((size_t)NN*4);
  float* h_a    = (float*)alloc((size_t)NN*128*4);
  unsigned short* hbf  = (unsigned short*)alloc((size_t)NN*128*2);
  unsigned short* aggb = (unsigned short*)alloc((size_t)NN*512*2);
  unsigned short* blay = (unsigned short*)alloc((size_t)8192*8*2);
  unsigned short* dwb  = (unsigned short*)alloc((size_t)256*8*2);
  float* usd    = (float*)alloc((size_t)1024*4);
  float* sum_s  = (float*)alloc((size_t)NN*4*4);
  float* sum_d  = (float*)alloc((size_t)NN*4*4);
  float* logits = (float*)alloc((size_t)NET*4*4);
  unsigned short* alphab = (unsigned short*)alloc((size_t)NET*4*2);
  float* xp     = (float*)alloc((size_t)NK*128*4);
  unsigned short* xpb = (unsigned short*)alloc((size_t)NK*128*2);
  float* sA     = (float*)alloc((size_t)NK*16*4);
  float* tbuf   = (float*)alloc((size_t)NK*16*4);
  float* deg    = (float*)alloc((size_t)NK*4);
  float* acc    = (float*)alloc((size_t)ACC_FLOATS*4);
  float* hh_g   = (float*)alloc((size_t)8192*4);

  k_init<<<256, 256, 0, stream>>>(csr_fill, node2k, tbuf, deg, acc);
  k_prepdw<<<1, 256, 0, stream>>>(dmon_w, dwb);
  k_count<<<(NET+255)/256, 256, 0, stream>>>(ei, csr_fill);
  k_scan<<<1, 1024, 0, stream>>>(csr_fill, csr_ptr, csr_fill);
  k_fill<<<(NET+255)/256, 256, 0, stream>>>(ei, csr_fill, csr_src);
  k_embed<<<(NN*32+255)/256, 256, 0, stream>>>(x, node_emb, (float4*)h_a, hbf);

  for (int l=0;l<3;l++){
    k_prepc<<<33, 256, 0, stream>>>(W[l], As_[l], Ad_[l], usd, blay);
    k_attnsum<<<NN, 64, 0, stream>>>(hbf, usd, sum_s, sum_d);
    k_edges<<<(NN*NH+255)/256, 256, 0, stream>>>(csr_ptr, csr_src, sum_s, sum_d, logits, alphab);
    k_agg<<<NN, 128, 0, stream>>>(csr_ptr, csr_src, alphab, hbf, aggb);
    k_gemmb<<<NN/64, 256, 0, stream>>>(aggb, blay, Bb[l], h_a, hbf);
  }
  // h_a = final node features (fp32), hbf = bf16 copy
  k_pq<<<NN, 64, 0, stream>>>(h_a, wrel, wroot, pbuf, qbuf);
  k_sagscore<<<(NN+255)/256, 256, 0, stream>>>(csr_ptr, csr_src, pbuf, qbuf, brel, score);
  k_topk<<<1, 1024, 0, stream>>>(score, sel);
  k_gatherx<<<NK, 128, 0, stream>>>(sel, score, h_a, xp, xpb, node2k);
  k_assignm<<<NK/16, 64, 0, stream>>>(xpb, dwb, dmon_b, sA);
  k_edgepool<<<(NE+255)/256, 256, 0, stream>>>(ei, node2k, sA, tbuf, deg);
  k_pool<<<P_BLOCKS, 256, 0, stream>>>(sA, xp, tbuf, deg, acc);
  k_finloss<<<1, 256, 0, stream>>>(acc, dout);
  k_hh<<<32, 256, 0, stream>>>(acc, Wt, hh_g);
  k_head<<<1, 256, 0, stream>>>(hh_g, acc, att_s, att_d, btb, gate_w, gate_b,
                                trans_w, trans_b, task, task_emb, task_w, task_b,
                                fuse_w, fuse_b, out_w, out_b, dout);
}

// Round 9
// 515.125 us; speedup vs baseline: 1.1697x; 1.1697x over previous
//
#include <hip/hip_runtime.h>
#include <hip/hip_bf16.h>
#include <math.h>

// Problem constants
constexpr int NN  = 16000;          // nodes
constexpr int NE  = 256000;         // edges (original)
constexpr int NET = NE + NN;        // edges incl. self loops
constexpr int NK  = 4000;           // top-k
constexpr int NH  = 4;              // heads
constexpr int ND  = 128;            // dim
constexpr int NCL = 16;             // clusters

// acc buffer sub-offsets (floats)
constexpr int A_ADJ    = 0;     // 256  raw s^T adj s
constexpr int A_SS     = 256;   // 256  s^T s
constexpr int A_CSUM   = 512;   // 16   sum_n s[n,c]
constexpr int A_V      = 528;   // 16   sum_n s[n,c]*deg[n]
constexpr int A_DEGSUM = 544;   // 1
constexpr int A_OUTX   = 560;   // 2048 s^T xp (selu'd in k_finloss)
constexpr int A_ADJN   = 2608;  // 256  normalized adjacency
constexpr int ACC_FLOATS = 3072;

typedef short sh8 __attribute__((ext_vector_type(8)));
typedef float f32x4 __attribute__((ext_vector_type(4)));

__device__ inline unsigned fkey(float f){
  unsigned u = __float_as_uint(f);
  return (u & 0x80000000u) ? ~u : (u | 0x80000000u);
}

__device__ inline unsigned short f2bf(float f){
  unsigned u = __float_as_uint(f);
  unsigned r = u + 0x7FFFu + ((u>>16)&1u);   // round-to-nearest-even
  return (unsigned short)(r>>16);
}

__device__ inline float bflo(unsigned v){ return __uint_as_float(v<<16); }
__device__ inline float bfhi(unsigned v){ return __uint_as_float(v & 0xFFFF0000u); }

// ---------------- init (+ dmon_w MFMA pack in block 0) ----------------
__global__ void k_init(int* cnt, int* node2k, float* tbuf, float* deg, float* acc,
                       const float* __restrict__ dw, unsigned short* __restrict__ dwb){
  int i = blockIdx.x*blockDim.x + threadIdx.x;
  int stride = gridDim.x*blockDim.x;
  for (int j=i; j<NN; j+=stride){ cnt[j]=0; node2k[j]=-1; }
  for (int j=i; j<NK*NCL; j+=stride) tbuf[j]=0.f;
  for (int j=i; j<NK; j+=stride) deg[j]=0.f;
  for (int j=i; j<ACC_FLOATS; j+=stride) acc[j]=0.f;
  if (blockIdx.x==0){
    int idx = threadIdx.x;            // 256 = 4 kc * 64 lanes
    int kc = idx>>6, lane = idx&63;
    int c = lane&15, q = lane>>4;
    sh8 v;
    #pragma unroll
    for (int j=0;j<8;j++) v[j] = (short)f2bf(dw[(size_t)c*128 + kc*32 + q*8 + j]);
    ((sh8*)dwb)[idx] = v;
  }
}

// ---------------- CSR build ----------------
__global__ void k_count(const int* __restrict__ ei, int* __restrict__ cnt){
  int e = blockIdx.x*blockDim.x + threadIdx.x;
  if (e >= NET) return;
  int d = (e < NE) ? ei[NE+e] : (e-NE);
  atomicAdd(&cnt[d], 1);
}

__global__ __launch_bounds__(1024) void k_scan(int* cnt, int* ptr, int* fill){
  __shared__ int sums[1024];
  int t = threadIdx.x;
  constexpr int PER = 16;            // 1024*16 = 16384 >= NN
  int base = t*PER;
  int v[PER];
  int run = 0;
  #pragma unroll
  for (int i=0;i<PER;i++){
    int idx = base+i;
    int c = (idx<NN)? cnt[idx] : 0;
    v[i] = run; run += c;
  }
  sums[t] = run;
  __syncthreads();
  for (int o=1;o<1024;o<<=1){
    int add = (t>=o)? sums[t-o] : 0;
    __syncthreads();
    sums[t] += add;
    __syncthreads();
  }
  int ex = sums[t] - run;
  #pragma unroll
  for (int i=0;i<PER;i++){
    int idx = base+i;
    if (idx<NN){ int p = ex+v[i]; ptr[idx]=p; fill[idx]=p; }
  }
  if (t==1023) ptr[NN]=sums[1023];
}

__global__ void k_fill(const int* __restrict__ ei, int* cur, int* csrc){
  int e = blockIdx.x*blockDim.x + threadIdx.x;
  if (e >= NET) return;
  int s, d;
  if (e < NE){ s = ei[e]; d = ei[NE+e]; } else { s = e-NE; d = e-NE; }
  int pos = atomicAdd(&cur[d], 1);
  csrc[pos] = s;
}

// ---------------- embedding (bf16 only; fp32 h not needed until final layer) ----
__global__ void k_embed(const int* __restrict__ x, const float* __restrict__ emb,
                        unsigned short* __restrict__ hbf){
  int i = blockIdx.x*blockDim.x + threadIdx.x;
  if (i >= NN*32) return;
  int n = i >> 5, q = i & 31;
  float4 v = ((const float4*)emb)[(size_t)x[n]*32 + q];
  ushort4 b;
  b.x = f2bf(v.x); b.y = f2bf(v.y); b.z = f2bf(v.z); b.w = f2bf(v.w);
  ((ushort4*)hbf)[i] = b;
}

// ---------------- combined per-layer prep: usd vectors + W pack ----------------
__global__ __launch_bounds__(256) void k_prepc(const float* __restrict__ W,
                                               const float* __restrict__ as_,
                                               const float* __restrict__ ad_,
                                               float* __restrict__ usd,
                                               unsigned short* __restrict__ Blay){
  int b = blockIdx.x;
  if (b < 32){
    int idx = b*256 + threadIdx.x;  // 0..8191
    int lane = idx&63, kc = (idx>>6)&15, c = idx>>10;
    int d = c*16 + (lane&15), q = lane>>4;
    sh8 v;
    #pragma unroll
    for (int j=0;j<8;j++){
      int kkg = kc*32 + q*8 + j;
      int h = kkg>>7, k = kkg&127;
      v[j] = (short)f2bf(W[(size_t)(h*128+d)*128 + k]);
    }
    *((sh8*)(Blay + (size_t)idx*8)) = v;
  } else {
    for (int t = threadIdx.x; t < 512; t += 256){
      int h = t>>7, k = t&127;
      float ss=0.f, sd=0.f;
      for (int d=0; d<128; d++){
        float w = W[(size_t)(h*128+d)*128 + k];
        ss += as_[h*128+d]*w;
        sd += ad_[h*128+d]*w;
      }
      usd[t] = ss;
      usd[512+t] = sd;
    }
  }
}

// ---------------- attention logit sums (bf16 features, ushort2 loads) ----------
__global__ __launch_bounds__(64) void k_attnsum(const unsigned short* __restrict__ hbf,
                          const float* __restrict__ usd,
                          float* __restrict__ sum_s, float* __restrict__ sum_d){
  int n = blockIdx.x, lane = threadIdx.x;   // 64 threads
  unsigned hv = *(const unsigned*)&hbf[(size_t)n*128 + 2*lane];
  float x0 = bflo(hv), x1 = bfhi(hv);
  #pragma unroll
  for (int h=0;h<4;h++){
    float2 us = *(const float2*)&usd[h*128 + 2*lane];
    float2 ud = *(const float2*)&usd[512 + h*128 + 2*lane];
    float ps = x0*us.x + x1*us.y;
    float pd = x0*ud.x + x1*ud.y;
    #pragma unroll
    for (int off=32; off>0; off>>=1){ ps += __shfl_down(ps,off); pd += __shfl_down(pd,off); }
    if (lane==0){ sum_s[n*4+h]=ps; sum_d[n*4+h]=pd; }
  }
}

// ---------------- edge softmax: one WAVE per node, lane per edge ----------------
__global__ __launch_bounds__(64) void k_edgesw(const int* __restrict__ ptr,
                        const int* __restrict__ csrc,
                        const float* __restrict__ sum_s, const float* __restrict__ sum_d,
                        unsigned short* __restrict__ alphab){
  int n = blockIdx.x; int lane = threadIdx.x;
  int b0 = ptr[n], b1 = ptr[n+1];
  int deg = b1 - b0;
  float4 sd = ((const float4*)sum_d)[n];
  int j0 = b0 + lane;
  bool act = lane < deg;
  float vx=-1e30f, vy=-1e30f, vz=-1e30f, vw=-1e30f;
  if (act){
    float4 ss = ((const float4*)sum_s)[csrc[j0]];
    vx = ss.x+sd.x; vx = vx>0.f? vx : 0.2f*vx;
    vy = ss.y+sd.y; vy = vy>0.f? vy : 0.2f*vy;
    vz = ss.z+sd.z; vz = vz>0.f? vz : 0.2f*vz;
    vw = ss.w+sd.w; vw = vw>0.f? vw : 0.2f*vw;
  }
  float mx=vx, my=vy, mz=vz, mw=vw;
  for (int base=64; base<deg; base+=64){
    int j = b0+base+lane;
    if (j<b1){
      float4 ss = ((const float4*)sum_s)[csrc[j]];
      float t0=ss.x+sd.x; t0=t0>0.f?t0:0.2f*t0; mx=fmaxf(mx,t0);
      float t1=ss.y+sd.y; t1=t1>0.f?t1:0.2f*t1; my=fmaxf(my,t1);
      float t2=ss.z+sd.z; t2=t2>0.f?t2:0.2f*t2; mz=fmaxf(mz,t2);
      float t3=ss.w+sd.w; t3=t3>0.f?t3:0.2f*t3; mw=fmaxf(mw,t3);
    }
  }
  #pragma unroll
  for (int o=1;o<64;o<<=1){
    mx=fmaxf(mx,__shfl_xor(mx,o)); my=fmaxf(my,__shfl_xor(my,o));
    mz=fmaxf(mz,__shfl_xor(mz,o)); mw=fmaxf(mw,__shfl_xor(mw,o));
  }
  float dx = act? __expf(vx-mx):0.f, dy = act? __expf(vy-my):0.f;
  float dz = act? __expf(vz-mz):0.f, dw = act? __expf(vw-mw):0.f;
  for (int base=64; base<deg; base+=64){
    int j = b0+base+lane;
    if (j<b1){
      float4 ss = ((const float4*)sum_s)[csrc[j]];
      float t0=ss.x+sd.x; t0=t0>0.f?t0:0.2f*t0; dx+=__expf(t0-mx);
      float t1=ss.y+sd.y; t1=t1>0.f?t1:0.2f*t1; dy+=__expf(t1-my);
      float t2=ss.z+sd.z; t2=t2>0.f?t2:0.2f*t2; dz+=__expf(t2-mz);
      float t3=ss.w+sd.w; t3=t3>0.f?t3:0.2f*t3; dw+=__expf(t3-mw);
    }
  }
  #pragma unroll
  for (int o=1;o<64;o<<=1){
    dx+=__shfl_xor(dx,o); dy+=__shfl_xor(dy,o);
    dz+=__shfl_xor(dz,o); dw+=__shfl_xor(dw,o);
  }
  float scx = 0.25f/(dx+1e-16f), scy = 0.25f/(dy+1e-16f);
  float scz = 0.25f/(dz+1e-16f), scw = 0.25f/(dw+1e-16f);
  if (act){
    ushort4 o4;
    o4.x = f2bf(__expf(vx-mx)*scx); o4.y = f2bf(__expf(vy-my)*scy);
    o4.z = f2bf(__expf(vz-mz)*scz); o4.w = f2bf(__expf(vw-mw)*scw);
    *(ushort4*)&alphab[(size_t)j0*4] = o4;
  }
  for (int base=64; base<deg; base+=64){
    int j = b0+base+lane;
    if (j<b1){
      float4 ss = ((const float4*)sum_s)[csrc[j]];
      float t0=ss.x+sd.x; t0=t0>0.f?t0:0.2f*t0;
      float t1=ss.y+sd.y; t1=t1>0.f?t1:0.2f*t1;
      float t2=ss.z+sd.z; t2=t2>0.f?t2:0.2f*t2;
      float t3=ss.w+sd.w; t3=t3>0.f?t3:0.2f*t3;
      ushort4 o4;
      o4.x=f2bf(__expf(t0-mx)*scx); o4.y=f2bf(__expf(t1-my)*scy);
      o4.z=f2bf(__expf(t2-mz)*scz); o4.w=f2bf(__expf(t3-mw)*scw);
      *(ushort4*)&alphab[(size_t)j*4] = o4;
    }
  }
}

// ---------------- input-space aggregation (64 thr, ushort2 loads, bf16 out) ------
__global__ __launch_bounds__(64) void k_agg(const int* __restrict__ ptr,
                      const int* __restrict__ csrc,
                      const unsigned short* __restrict__ alphab,
                      const unsigned short* __restrict__ hbf,
                      unsigned short* __restrict__ agg){
  int n = blockIdx.x; int t = threadIdx.x;  // 64 threads, 2 features each
  int b0 = ptr[n], b1 = ptr[n+1];
  float a00=0.f,a01=0.f,a10=0.f,a11=0.f,a20=0.f,a21=0.f,a30=0.f,a31=0.f;
  for (int j=b0;j<b1;j++){
    int s = csrc[j];
    uint2 al = *(const uint2*)&alphab[(size_t)j*4];
    float ax = bflo(al.x), ay = bfhi(al.x);
    float az = bflo(al.y), aw = bfhi(al.y);
    unsigned hv = *(const unsigned*)&hbf[(size_t)s*128 + 2*t];
    float v0 = bflo(hv), v1 = bfhi(hv);
    a00 += ax*v0; a01 += ax*v1;
    a10 += ay*v0; a11 += ay*v1;
    a20 += az*v0; a21 += az*v1;
    a30 += aw*v0; a31 += aw*v1;
  }
  unsigned short* o = agg + (size_t)n*512;
  *(ushort2*)&o[      2*t] = (ushort2){f2bf(a00), f2bf(a01)};
  *(ushort2*)&o[128 + 2*t] = (ushort2){f2bf(a10), f2bf(a11)};
  *(ushort2*)&o[256 + 2*t] = (ushort2){f2bf(a20), f2bf(a21)};
  *(ushort2*)&o[384 + 2*t] = (ushort2){f2bf(a30), f2bf(a31)};
}

// ---------------- MFMA head-transform GEMM ----------
__global__ __launch_bounds__(256) void k_gemmb(const unsigned short* __restrict__ A,
                                               const unsigned short* __restrict__ B,
                                               const float* __restrict__ bias,
                                               float* __restrict__ C,        // may be null
                                               unsigned short* __restrict__ Cb,
                                               int writeF32){
  int tid = threadIdx.x;
  int w = tid>>6, lane = tid&63;
  int m0 = blockIdx.x*64 + w*16;
  int quad = lane>>4;
  int mrow = m0 + (lane&15);
  const sh8* arow = (const sh8*)(A + (size_t)mrow*512 + quad*8);
  sh8 af[16];
  #pragma unroll
  for (int kc=0;kc<16;kc++) af[kc] = arow[kc*4];
  f32x4 acc[8];
  #pragma unroll
  for (int c=0;c<8;c++) acc[c] = (f32x4){0.f,0.f,0.f,0.f};
  const sh8* bp = (const sh8*)B;
  #pragma unroll
  for (int kc=0;kc<16;kc++){
    #pragma unroll
    for (int c=0;c<8;c++){
      sh8 bf = bp[(c*16+kc)*64 + lane];
      acc[c] = __builtin_amdgcn_mfma_f32_16x16x32_bf16(af[kc], bf, acc[c], 0, 0, 0);
    }
  }
  #pragma unroll
  for (int c=0;c<8;c++){
    int d = c*16 + (lane&15);
    float bi = bias[d];
    #pragma unroll
    for (int r=0;r<4;r++){
      int m = m0 + quad*4 + r;
      float v = fmaxf(acc[c][r] + bi, 0.f);
      Cb[(size_t)m*128 + d] = f2bf(v);
      if (writeF32) C[(size_t)m*128 + d] = v;
    }
  }
}

// ---------------- SAG score: p,q per node ----------------
__global__ __launch_bounds__(64) void k_pq(const float* __restrict__ h,
                     const float* __restrict__ wrel,
                     const float* __restrict__ wroot, float* __restrict__ p,
                     float* __restrict__ q){
  int n = blockIdx.x; int lane = threadIdx.x; // 64
  const float* row = h+(size_t)n*128;
  float a = row[lane]*wrel[lane] + row[64+lane]*wrel[64+lane];
  float b = row[lane]*wroot[lane] + row[64+lane]*wroot[64+lane];
  #pragma unroll
  for (int o=32;o>0;o>>=1){ a += __shfl_down(a,o); b += __shfl_down(b,o); }
  if (lane==0){ p[n]=a; q[n]=b; }
}

// wave per node, lane-parallel neighbor gather
__global__ __launch_bounds__(64) void k_sagw(const int* __restrict__ ptr,
                           const int* __restrict__ csrc,
                           const float* __restrict__ p, const float* __restrict__ q,
                           const float* __restrict__ brel, float* __restrict__ score){
  int n = blockIdx.x; int lane = threadIdx.x;
  int b0=ptr[n], b1=ptr[n+1];
  float s=0.f;
  for (int j=b0+lane; j<b1; j+=64){
    int sj=csrc[j];
    if (sj!=n) s+=p[sj];
  }
  #pragma unroll
  for (int o=32;o>0;o>>=1) s += __shfl_down(s,o);
  if (lane==0) score[n] = s + q[n] + brel[0];
}

// ---------------- fused single-block radix top-k (register-resident keys) ----------------
__global__ __launch_bounds__(1024) void k_topk(const float* __restrict__ score,
                                               int* __restrict__ sel){
  __shared__ int hist[8*257];
  __shared__ int hmerge[256];
  __shared__ unsigned sh_prefix;
  __shared__ int sh_rem;
  __shared__ int cntGT, cntEQ;
  __shared__ int ties[256];
  int t = threadIdx.x;
  int lane = t & 63;
  int rep = t >> 7;
  unsigned keys[16];
  #pragma unroll
  for (int j=0;j<16;j++){
    int i = t + j*1024;
    keys[j] = (i<NN) ? fkey(score[i]) : 0u;
  }
  if (t==0){ sh_prefix=0u; sh_rem=NK; cntGT=0; cntEQ=0; }
  __syncthreads();
  for (int p=0;p<4;p++){
    int shift = 24-8*p;
    for (int i=t;i<8*257;i+=1024) hist[i]=0;
    __syncthreads();
    unsigned prefix = sh_prefix;
    #pragma unroll
    for (int j=0;j<16;j++){
      bool val = (j<15) || (t < (NN - 15*1024));
      unsigned u = keys[j];
      bool ok = val && ((p==0) || ((u>>(shift+8)) == (prefix>>(shift+8))));
      int b = (int)((u>>shift)&255u);
      unsigned long long act = __ballot(ok);
      if (act){
        int leader = (int)(__ffsll((long long)act)-1);
        int bl = __shfl(b, leader);
        unsigned long long same = __ballot(ok && b==bl);
        if (same==act){
          if (lane==leader) atomicAdd(&hist[rep*257+bl], (int)__popcll(act));
        } else if (ok){
          atomicAdd(&hist[rep*257+b], 1);
        }
      }
    }
    __syncthreads();
    if (t<256){
      int v=0;
      #pragma unroll
      for (int r=0;r<8;r++) v += hist[r*257+t];
      hmerge[t]=v;
    }
    __syncthreads();
    if (t<64){
      int l = t;
      int b0 = 4*(63-l);
      int c3 = hmerge[b0+3], c2 = hmerge[b0+2], c1 = hmerge[b0+1], c0 = hmerge[b0];
      int gs = c0+c1+c2+c3;
      int incl = gs;
      #pragma unroll
      for (int o=1;o<64;o<<=1){
        int v = __shfl_up(incl, o);
        if (l>=o) incl += v;
      }
      int excl = incl - gs;
      int rem = sh_rem;
      int rl = rem - excl;
      if (rl > 0 && rl <= gs){
        unsigned pre = sh_prefix;
        if (rl > c3){ rl -= c3;
          if (rl > c2){ rl -= c2;
            if (rl > c1){ rl -= c1;
              sh_prefix = pre | ((unsigned)b0<<shift);     sh_rem = rl;
            } else { sh_prefix = pre | ((unsigned)(b0+1)<<shift); sh_rem = rl; }
          } else { sh_prefix = pre | ((unsigned)(b0+2)<<shift);   sh_rem = rl; }
        } else { sh_prefix = pre | ((unsigned)(b0+3)<<shift);     sh_rem = rl; }
      }
    }
    __syncthreads();
  }
  unsigned Tu = sh_prefix;
  #pragma unroll
  for (int j=0;j<16;j++){
    int i = t + j*1024;
    bool val = (i<NN);
    unsigned u = keys[j];
    bool g = val && (u>Tu), e = val && (u==Tu);
    unsigned long long mg = __ballot(g);
    if (mg){
      int leader = (int)(__ffsll((long long)mg)-1);
      int base = 0;
      if (lane==leader) base = atomicAdd(&cntGT, (int)__popcll(mg));
      base = __shfl(base, leader);
      if (g){
        int pos = base + (int)__popcll(mg & ((1ull<<lane)-1ull));
        sel[pos] = i;
      }
    }
    unsigned long long me = __ballot(e);
    if (me){
      int leader = (int)(__ffsll((long long)me)-1);
      int base = 0;
      if (lane==leader) base = atomicAdd(&cntEQ, (int)__popcll(me));
      base = __shfl(base, leader);
      if (e){
        int pos = base + (int)__popcll(me & ((1ull<<lane)-1ull));
        if (pos<256) ties[pos] = i;
      }
    }
  }
  __syncthreads();
  if (t==0){
    int base=cntGT, rem=sh_rem, nt=min(cntEQ,256);
    for (int r=0;r<rem;r++){
      int best=0x7fffffff, bi=-1;
      for (int q2=0;q2<nt;q2++){ int v=ties[q2]; if (v>=0 && v<best){best=v;bi=q2;} }
      sel[base+r] = (bi>=0)? best : 0;
      if (bi>=0) ties[bi]=-1;
    }
  }
}

// ---------------- fused xp gather + node2k + DMoN assignment (MFMA) ----------------
// block = 256 threads, handles 16 pooled rows; xp bf16 staged in LDS for MFMA.
__global__ __launch_bounds__(256) void k_gassign(const int* __restrict__ sel,
                          const float* __restrict__ score,
                          const float* __restrict__ h, float* __restrict__ xp,
                          int* __restrict__ node2k,
                          const unsigned short* __restrict__ dwb,
                          const float* __restrict__ db,
                          float* __restrict__ sA){
  __shared__ unsigned short xs[16*128];
  __shared__ int seln[16];
  __shared__ float gs[16];
  int k0 = blockIdx.x*16;
  int t = threadIdx.x;
  if (t<16){
    int n = sel[k0+t];
    seln[t] = n;
    node2k[n] = k0+t;
    gs[t] = tanhf(score[n]);
  }
  __syncthreads();
  #pragma unroll
  for (int it=0; it<8; it++){
    int idx = t + it*256;
    int row = idx>>7, col = idx&127;
    float v = h[(size_t)seln[row]*128 + col]*gs[row];
    xp[(size_t)(k0+row)*128 + col] = v;
    xs[idx] = f2bf(v);
  }
  __syncthreads();
  if (t<64){
    int lane = t;
    int quad = lane>>4, col = lane&15;
    const sh8* ar = (const sh8*)&xs[col*128 + quad*8];
    const sh8* br = (const sh8*)dwb;
    f32x4 acc = (f32x4){0.f,0.f,0.f,0.f};
    #pragma unroll
    for (int kc=0;kc<4;kc++){
      sh8 af = ar[kc*4];
      sh8 bf = br[kc*64 + lane];
      acc = __builtin_amdgcn_mfma_f32_16x16x32_bf16(af, bf, acc, 0, 0, 0);
    }
    float bias = db[col];
    #pragma unroll
    for (int r=0;r<4;r++){
      float lg = acc[r] + bias;
      float mx = lg;
      #pragma unroll
      for (int o=1;o<16;o<<=1) mx = fmaxf(mx, __shfl_xor(mx, o));
      float e = __expf(lg - mx);
      float sm = e;
      #pragma unroll
      for (int o=1;o<16;o<<=1) sm += __shfl_xor(sm, o);
      sA[(size_t)(k0+quad*4+r)*16 + col] = e/sm;
    }
  }
}

// ---------------- pooled adjacency ----------------
__global__ void k_edgepool(const int* __restrict__ ei, const int* __restrict__ node2k,
                           const float* __restrict__ sA, float* __restrict__ tbuf,
                           float* __restrict__ deg){
  int e = blockIdx.x*blockDim.x + threadIdx.x;
  if (e >= NE) return;
  int ni = node2k[ei[e]];
  int nj = node2k[ei[NE+e]];
  if (ni >= 0 && nj >= 0){
    atomicAdd(&deg[nj], 1.f);
    const float* sr = &sA[(size_t)nj*16];
    float* tr = &tbuf[(size_t)ni*16];
    #pragma unroll
    for (int c=0;c<16;c++) atomicAdd(&tr[c], sr[c]);
  }
}

// ---------------- fused pooled reductions ----------------
constexpr int P_BLOCKS = 80;
constexpr int P_ROWS   = NK / P_BLOCKS;   // 50
constexpr int P_CHUNK  = 25;

__global__ __launch_bounds__(256) void k_pool(const float* __restrict__ sA,
                                              const float* __restrict__ xp,
                                              const float* __restrict__ tb,
                                              const float* __restrict__ deg,
                                              float* __restrict__ acc){
  __shared__ float sv[P_CHUNK*16];
  __shared__ float tv[P_CHUNK*16];
  __shared__ float dv[P_CHUNK];
  __shared__ float xv[P_CHUNK*128];
  int t = threadIdx.x;
  int c = t>>4, d = t&15;
  float loc[8] = {0,0,0,0,0,0,0,0};
  float a_adj=0.f, a_ss=0.f, a_cs=0.f, a_v=0.f, a_dg=0.f;
  int r0 = blockIdx.x*P_ROWS;
  for (int ch=0; ch<P_ROWS; ch+=P_CHUNK){
    int base = r0+ch;
    for (int i=t;i<P_CHUNK*16;i+=256){
      sv[i] = sA[(size_t)(base+(i>>4))*16 + (i&15)];
      tv[i] = tb[(size_t)(base+(i>>4))*16 + (i&15)];
    }
    for (int i=t;i<P_CHUNK*128;i+=256)
      xv[i] = xp[(size_t)(base+(i>>7))*128 + (i&127)];
    if (t<P_CHUNK) dv[t]=deg[base+t];
    __syncthreads();
    for (int r=0;r<P_CHUNK;r++){
      float sc = sv[r*16+c];
      a_adj += sc*tv[r*16+d];
      a_ss  += sc*sv[r*16+d];
      if (d==0){ a_cs += sc; a_v += sc*dv[r]; }
      if (t==0) a_dg += dv[r];
      #pragma unroll
      for (int j=0;j<8;j++){
        int o=t+j*256;
        loc[j] += sv[r*16+(o>>7)]*xv[r*128+(o&127)];
      }
    }
    __syncthreads();
  }
  atomicAdd(&acc[A_ADJ + t], a_adj);
  atomicAdd(&acc[A_SS + t], a_ss);
  if (d==0){ atomicAdd(&acc[A_CSUM+c], a_cs); atomicAdd(&acc[A_V+c], a_v); }
  if (t==0) atomicAdd(&acc[A_DEGSUM], a_dg);
  #pragma unroll
  for (int j=0;j<8;j++) atomicAdd(&acc[A_OUTX + t + j*256], loc[j]);
}

__device__ float block_sum_256(float v, float* red){
  int t = threadIdx.x;
  red[t]=v; __syncthreads();
  #pragma unroll
  for (int o=128;o>0;o>>=1){ if (t<o) red[t]+=red[t+o]; __syncthreads(); }
  float r = red[0]; __syncthreads();
  return r;
}

// ---------------- losses + normalized adjacency + selu(out_x) ----------------
__global__ __launch_bounds__(256) void k_finloss(float* __restrict__ acc, float* __restrict__ dout){
  __shared__ float red[256];
  __shared__ float dsv[16];
  int t = threadIdx.x;
  int c = t>>4, dcol = t&15;
  float m = 0.5f*acc[A_DEGSUM];
  float ssv = acc[A_SS+t];
  float tr    = block_sum_256((t<16)? acc[A_ADJ + t*16 + t] : 0.f, red);
  float sumv2 = block_sum_256((t<16)? acc[A_V+t]*acc[A_V+t] : 0.f, red);
  float ss2   = block_sum_256(ssv*ssv, red);
  float cs2   = block_sum_256((t<16)? acc[A_CSUM+t]*acc[A_CSUM+t] : 0.f, red);
  float ssn = sqrtf(ss2);
  float term = ssv/ssn - ((c==dcol)? 0.25f : 0.f);
  float ortho2 = block_sum_256(term*term, red);
  if (t==0){
    float spectral = -(tr - sumv2/(2.f*m))/(2.f*m);
    float ortho = sqrtf(ortho2);
    float cluster = sqrtf(cs2)/(float)NK*4.f - 1.f;
    dout[1] = spectral + ortho + cluster;
  }
  float z = (c==dcol)? 0.f : acc[A_ADJ+t];
  red[t]=z; __syncthreads();
  for (int o=8;o>0;o>>=1){ if (dcol<o) red[t]+=red[t+o]; __syncthreads(); }
  if (dcol==0) dsv[c]=sqrtf(red[c*16])+1e-15f;
  __syncthreads();
  acc[A_ADJN+t] = z/(dsv[c]*dsv[dcol]);
  #pragma unroll
  for (int j=0;j<8;j++){
    int idx = t + j*256;
    float xv = acc[A_OUTX+idx];
    float s2 = (xv > 0.f)? xv : 1.6732632423543772f*expm1f(xv);
    acc[A_OUTX+idx] = 1.0507009873554805f*s2;
  }
}

// ---------------- hh = selu(out_x) @ Wt^T ----------------
__global__ void k_hh(const float* __restrict__ acc, const float* __restrict__ Wt,
                     float* __restrict__ hh){
  int of = blockIdx.x*256 + threadIdx.x; // 0..8191
  int c = of >> 9, o = of & 511;
  const float* sx = acc + A_OUTX + c*128;
  const float* w = Wt + (size_t)o*128;
  float s=0.f;
  for (int k=0;k<128;k++) s += sx[k]*w[k];
  hh[of] = s;
}

// ---------------- dense GAT head + readout ----------------
__global__ __launch_bounds__(256) void k_head(
    const float* __restrict__ hh_g, const float* __restrict__ acc,
    const float* __restrict__ att_s, const float* __restrict__ att_d,
    const float* __restrict__ bt, const float* __restrict__ gate_w,
    const float* __restrict__ gate_b, const float* __restrict__ trans_w,
    const float* __restrict__ trans_b, const int* __restrict__ task,
    const float* __restrict__ task_emb, const float* __restrict__ task_w,
    const float* __restrict__ task_b, const float* __restrict__ fuse_w,
    const float* __restrict__ fuse_b, const float* __restrict__ out_w,
    const float* __restrict__ out_b, float* __restrict__ dout){
  __shared__ float hh[8192];
  __shared__ float al[1024];
  __shared__ float asrc[64], adst[64];
  __shared__ float dg[2048];
  __shared__ float gate[16];
  __shared__ float gvec[128];
  __shared__ float ro[128], te[128], fu[128];
  __shared__ float red[256];
  int t = threadIdx.x;
  for (int i=t;i<8192;i+=256) hh[i]=hh_g[i];
  __syncthreads();
  if (t<128){
    int j = t>>3; int h = (t>>1)&3; int w = t&1;
    const float* hr = &hh[j*512 + h*128];
    const float* a = (w? att_d : att_s) + h*128;
    float s=0.f;
    for (int k2=0;k2<128;k2++) s += hr[k2]*a[k2];
    if (w) adst[j*4+h]=s; else asrc[j*4+h]=s;
  }
  __syncthreads();
  for (int idx=t; idx<1024; idx+=256){
    int h = idx&3, j=(idx>>2)&15, i=idx>>6;
    float v = asrc[j*4+h] + adst[i*4+h];
    v = v>0.f? v : 0.2f*v;
    float adjl = (i==j)? 1.f : acc[A_ADJN + i*16+j];
    al[idx] = (adjl==0.f)? -1e30f : v;
  }
  __syncthreads();
  if (t<64){
    int i=t>>2, h=t&3;
    float mx=-1e30f;
    for (int j=0;j<16;j++) mx = fmaxf(mx, al[(i*16+j)*4+h]);
    float sum=0.f;
    for (int j=0;j<16;j++){ float e=__expf(al[(i*16+j)*4+h]-mx); al[(i*16+j)*4+h]=e; sum+=e; }
    float inv = 1.f/sum;
    for (int j=0;j<16;j++) al[(i*16+j)*4+h]*=inv;
  }
  __syncthreads();
  for (int idx=t; idx<2048; idx+=256){
    int i=idx>>7, d=idx&127;
    float s=0.f;
    for (int h=0;h<4;h++)
      for (int j=0;j<16;j++)
        s += al[(i*16+j)*4+h]*hh[j*512+h*128+d];
    dg[idx] = fmaxf(0.25f*s + bt[d], 0.f);
  }
  __syncthreads();
  if (t<16){
    float s=0.f;
    for (int d2=0;d2<128;d2++) s += dg[t*128+d2]*gate_w[d2];
    red[t] = s + gate_b[0];
  }
  __syncthreads();
  if (t<16){
    float mx=-1e30f; for (int i=0;i<16;i++) mx=fmaxf(mx,red[i]);
    float s=0.f; for (int i=0;i<16;i++) s+=__expf(red[i]-mx);
    gate[t]=__expf(red[t]-mx)/s;
  }
  __syncthreads();
  if (t<128){
    float s=0.f;
    for (int i=0;i<16;i++) s += gate[i]*dg[i*128+t];
    gvec[t]=s;
  }
  __syncthreads();
  if (t<128){
    float s=0.f;
    for (int k2=0;k2<128;k2++) s += gvec[k2]*trans_w[t*128+k2];
    ro[t]=s+trans_b[t];
    int tk = task[0];
    float s2=0.f;
    for (int k2=0;k2<128;k2++) s2 += task_emb[(size_t)tk*128+k2]*task_w[t*128+k2];
    te[t]=fmaxf(s2+task_b[t],0.f);
  }
  __syncthreads();
  if (t<128){
    float s=0.f;
    for (int k2=0;k2<128;k2++) s += ro[k2]*fuse_w[t*256+k2] + te[k2]*fuse_w[t*256+128+k2];
    fu[t]=fmaxf(s+fuse_b[t],0.f);
  }
  __syncthreads();
  float v = (t<128)? fu[t]*out_w[t] : 0.f;
  red[t]=v; __syncthreads();
  for (int o=128;o>0;o>>=1){ if (t<o) red[t]+=red[t+o]; __syncthreads(); }
  if (t==0) dout[0]=red[0]+out_b[0];
}

// ================= launcher =================
extern "C" void kernel_launch(void* const* d_in, const int* in_sizes, int n_in,
                              void* d_out, int out_size, void* d_ws, size_t ws_size,
                              hipStream_t stream){
  const int* x        = (const int*)d_in[0];
  const int* ei       = (const int*)d_in[1];
  const int* task     = (const int*)d_in[3];
  const float* node_emb = (const float*)d_in[4];
  const float* task_emb = (const float*)d_in[5];
  const float* W[3]  = {(const float*)d_in[6],  (const float*)d_in[10], (const float*)d_in[14]};
  const float* As_[3]= {(const float*)d_in[7],  (const float*)d_in[11], (const float*)d_in[15]};
  const float* Ad_[3]= {(const float*)d_in[8],  (const float*)d_in[12], (const float*)d_in[16]};
  const float* Bb[3] = {(const float*)d_in[9],  (const float*)d_in[13], (const float*)d_in[17]};
  const float* wrel  = (const float*)d_in[18];
  const float* brel  = (const float*)d_in[19];
  const float* wroot = (const float*)d_in[20];
  const float* dmon_w= (const float*)d_in[21];
  const float* dmon_b= (const float*)d_in[22];
  const float* Wt    = (const float*)d_in[23];
  const float* att_s = (const float*)d_in[24];
  const float* att_d = (const float*)d_in[25];
  const float* btb   = (const float*)d_in[26];
  const float* gate_w= (const float*)d_in[27];
  const float* gate_b= (const float*)d_in[28];
  const float* trans_w=(const float*)d_in[29];
  const float* trans_b=(const float*)d_in[30];
  const float* task_w= (const float*)d_in[31];
  const float* task_b= (const float*)d_in[32];
  const float* fuse_w= (const float*)d_in[33];
  const float* fuse_b= (const float*)d_in[34];
  const float* out_w = (const float*)d_in[35];
  const float* out_b = (const float*)d_in[36];
  float* dout = (float*)d_out;
  (void)in_sizes; (void)n_in; (void)out_size; (void)ws_size;

  char* base = (char*)d_ws;
  size_t off = 0;
  auto alloc = [&](size_t bytes)->char*{
    off = (off + 255) & ~(size_t)255;
    char* r = base + off; off += bytes; return r;
  };
  int* csr_ptr  = (int*)alloc((size_t)(NN+1)*4);
  int* csr_fill = (int*)alloc((size_t)NN*4);
  int* csr_src  = (int*)alloc((size_t)NET*4);
  int* sel      = (int*)alloc((size_t)NK*4);
  int* node2k   = (int*)alloc((size_t)NN*4);
  float* score  = (float*)alloc((size_t)NN*4);
  float* pbuf   = (float*)alloc((size_t)NN*4);
  float* qbuf   = (float*)alloc((size_t)NN*4);
  float* h_a    = (float*)alloc((size_t)NN*128*4);
  unsigned short* hbf  = (unsigned short*)alloc((size_t)NN*128*2);
  unsigned short* aggb = (unsigned short*)alloc((size_t)NN*512*2);
  unsigned short* blay = (unsigned short*)alloc((size_t)8192*8*2);
  unsigned short* dwb  = (unsigned short*)alloc((size_t)256*8*2);
  float* usd    = (float*)alloc((size_t)1024*4);
  float* sum_s  = (float*)alloc((size_t)NN*4*4);
  float* sum_d  = (float*)alloc((size_t)NN*4*4);
  unsigned short* alphab = (unsigned short*)alloc((size_t)NET*4*2);
  float* xp     = (float*)alloc((size_t)NK*128*4);
  float* sA     = (float*)alloc((size_t)NK*16*4);
  float* tbuf   = (float*)alloc((size_t)NK*16*4);
  float* deg    = (float*)alloc((size_t)NK*4);
  float* acc    = (float*)alloc((size_t)ACC_FLOATS*4);
  float* hh_g   = (float*)alloc((size_t)8192*4);

  k_init<<<256, 256, 0, stream>>>(csr_fill, node2k, tbuf, deg, acc, dmon_w, dwb);
  k_count<<<(NET+255)/256, 256, 0, stream>>>(ei, csr_fill);
  k_scan<<<1, 1024, 0, stream>>>(csr_fill, csr_ptr, csr_fill);
  k_fill<<<(NET+255)/256, 256, 0, stream>>>(ei, csr_fill, csr_src);
  k_embed<<<(NN*32+255)/256, 256, 0, stream>>>(x, node_emb, hbf);

  for (int l=0;l<3;l++){
    k_prepc<<<33, 256, 0, stream>>>(W[l], As_[l], Ad_[l], usd, blay);
    k_attnsum<<<NN, 64, 0, stream>>>(hbf, usd, sum_s, sum_d);
    k_edgesw<<<NN, 64, 0, stream>>>(csr_ptr, csr_src, sum_s, sum_d, alphab);
    k_agg<<<NN, 64, 0, stream>>>(csr_ptr, csr_src, alphab, hbf, aggb);
    k_gemmb<<<NN/64, 256, 0, stream>>>(aggb, blay, Bb[l], h_a, hbf, (l==2)?1:0);
  }
  // h_a = final node features (fp32), hbf = bf16 copy
  k_pq<<<NN, 64, 0, stream>>>(h_a, wrel, wroot, pbuf, qbuf);
  k_sagw<<<NN, 64, 0, stream>>>(csr_ptr, csr_src, pbuf, qbuf, brel, score);
  k_topk<<<1, 1024, 0, stream>>>(score, sel);
  k_gassign<<<NK/16, 256, 0, stream>>>(sel, score, h_a, xp, node2k, dwb, dmon_b, sA);
  k_edgepool<<<(NE+255)/256, 256, 0, stream>>>(ei, node2k, sA, tbuf, deg);
  k_pool<<<P_BLOCKS, 256, 0, stream>>>(sA, xp, tbuf, deg, acc);
  k_finloss<<<1, 256, 0, stream>>>(acc, dout);
  k_hh<<<32, 256, 0, stream>>>(acc, Wt, hh_g);
  k_head<<<1, 256, 0, stream>>>(hh_g, acc, att_s, att_d, btb, gate_w, gate_b,
                                trans_w, trans_b, task, task_emb, task_w, task_b,
                                fuse_w, fuse_b, out_w, out_b, dout);
}